// Round 3
// 2697.981 us; speedup vs baseline: 1.0072x; 1.0072x over previous
//
#include <hip/hip_runtime.h>
#include <cstdint>
#include <cstddef>

// Problem constants (fixed by reference): B=16, N=M=2048, eps=0.05, 50 iters.
constexpr int B = 16, N = 2048, M = 2048;
constexpr int MAX_ITER = 50;
// exp(-cost/eps) = exp2(cost * C2), C2 = -(1/0.05) * log2(e)
#define C2 (-28.853900817779268f)

// Main path: 16 rows/chunk so each thread's K-tile share (16 uint4 = 64 VGPRs)
// stays register-resident across BOTH phases -> K read ONCE per iteration.
constexpr int ROWS_PER_CHUNK = 16;
constexpr int CHUNKS = N / ROWS_PER_CHUNK;   // 128

__device__ __forceinline__ unsigned short f2bf(float f) {
  union { float f; unsigned u; } x; x.f = f;
  unsigned r = x.u + 0x7fffu + ((x.u >> 16) & 1u);   // RNE; inputs finite positive
  return (unsigned short)(r >> 16);
}
__device__ __forceinline__ float bflo(unsigned w) { union { unsigned u; float f; } x; x.u = w << 16; return x.f; }
__device__ __forceinline__ float bfhi(unsigned w) { union { unsigned u; float f; } x; x.u = w & 0xffff0000u; return x.f; }

// ---------------- init: K = bf16(exp(-cost/eps)) ----------------
__global__ __launch_bounds__(256) void init_K(const float* __restrict__ cost,
                                              uint4* __restrict__ K) {
  unsigned gid = blockIdx.x * 256u + threadIdx.x;        // 4,194,304 threads x 16 elems
  const float4* c4 = (const float4*)cost;
  uint4 w0, w1;
  {
    float4 a = c4[(size_t)gid * 4 + 0];
    float4 b = c4[(size_t)gid * 4 + 1];
    w0.x = (unsigned)f2bf(exp2f(a.x * C2)) | ((unsigned)f2bf(exp2f(a.y * C2)) << 16);
    w0.y = (unsigned)f2bf(exp2f(a.z * C2)) | ((unsigned)f2bf(exp2f(a.w * C2)) << 16);
    w0.z = (unsigned)f2bf(exp2f(b.x * C2)) | ((unsigned)f2bf(exp2f(b.y * C2)) << 16);
    w0.w = (unsigned)f2bf(exp2f(b.z * C2)) | ((unsigned)f2bf(exp2f(b.w * C2)) << 16);
  }
  {
    float4 a = c4[(size_t)gid * 4 + 2];
    float4 b = c4[(size_t)gid * 4 + 3];
    w1.x = (unsigned)f2bf(exp2f(a.x * C2)) | ((unsigned)f2bf(exp2f(a.y * C2)) << 16);
    w1.y = (unsigned)f2bf(exp2f(a.z * C2)) | ((unsigned)f2bf(exp2f(a.w * C2)) << 16);
    w1.z = (unsigned)f2bf(exp2f(b.x * C2)) | ((unsigned)f2bf(exp2f(b.y * C2)) << 16);
    w1.w = (unsigned)f2bf(exp2f(b.z * C2)) | ((unsigned)f2bf(exp2f(b.w * C2)) << 16);
  }
  K[(size_t)gid * 2]     = w0;
  K[(size_t)gid * 2 + 1] = w1;
}

// ---------------- fused iteration kernel: single pass over K ----------------
// One WG per (chunk, b): 16 rows. Each thread loads its 16 uint4 (4 rows x 4
// column-groups) of K into VGPRs ONCE. Phase A: row dots vs v (shfl reduce) ->
// u. Phase B: column partials from the SAME registers; 4-wave LDS reduce ->
// part[b,chunk,:]. K bytes per iteration: 128 MiB (was 256 MiB).
template <bool FIRST>
__global__ __launch_bounds__(256, 4) void iter_fused(const uint4* __restrict__ K,
                                                     const float* __restrict__ r,
                                                     const float* __restrict__ v,
                                                     float* __restrict__ u_out,
                                                     float* __restrict__ part) {
  const int b = blockIdx.y, chunk = blockIdx.x;
  const int n0 = chunk * ROWS_PER_CHUNK;
  const int t = threadIdx.x;
  // smem: first used as v-staging (2048 floats), later (after phase-A sync)
  // reused as cpart[4][2048] for the cross-wave column reduce. Safe: all reads
  // of vs complete before the phase-A->B __syncthreads.
  __shared__ float smem[4 * 2048];
  __shared__ float us[ROWS_PER_CHUNK];
  float* vs = smem;

  if (FIRST) {
    float4 one; one.x = one.y = one.z = one.w = 1.0f;
    ((float4*)vs)[t] = one;
    ((float4*)vs)[t + 256] = one;
  } else {
    const float4* vv = (const float4*)(v + (size_t)b * M);
    ((float4*)vs)[t]       = vv[t];
    ((float4*)vs)[t + 256] = vv[t + 256];
  }

  const int wave = t >> 6, lane = t & 63;

  // Issue ALL K loads early (independent of vs) so HBM/L3 latency hides under
  // the barrier + vreg LDS reads. 16x16B = 256 B in flight per thread.
  uint4 kr[4][4];
#pragma unroll
  for (int rr = 0; rr < 4; ++rr) {
    const uint4* Kr = K + (size_t)(b * N + n0 + wave * 4 + rr) * (M / 8);
#pragma unroll
    for (int it = 0; it < 4; ++it) kr[rr][it] = Kr[it * 64 + lane];
  }

  __syncthreads();

  // Per-lane 32 v values in registers; same column mapping as kr.
  float vreg[32];
#pragma unroll
  for (int it = 0; it < 4; ++it) {
    float4 a = ((const float4*)vs)[it * 128 + lane * 2];
    float4 c = ((const float4*)vs)[it * 128 + lane * 2 + 1];
    vreg[it * 8 + 0] = a.x; vreg[it * 8 + 1] = a.y; vreg[it * 8 + 2] = a.z; vreg[it * 8 + 3] = a.w;
    vreg[it * 8 + 4] = c.x; vreg[it * 8 + 5] = c.y; vreg[it * 8 + 6] = c.z; vreg[it * 8 + 7] = c.w;
  }

  // Phase A: 4 rows per wave, from registers.
#pragma unroll
  for (int rr = 0; rr < 4; ++rr) {
    float acc = 0.f;
#pragma unroll
    for (int it = 0; it < 4; ++it) {
      uint4 w = kr[rr][it];
      acc += bflo(w.x) * vreg[it * 8 + 0] + bfhi(w.x) * vreg[it * 8 + 1]
           + bflo(w.y) * vreg[it * 8 + 2] + bfhi(w.y) * vreg[it * 8 + 3]
           + bflo(w.z) * vreg[it * 8 + 4] + bfhi(w.z) * vreg[it * 8 + 5]
           + bflo(w.w) * vreg[it * 8 + 6] + bfhi(w.w) * vreg[it * 8 + 7];
    }
#pragma unroll
    for (int off = 32; off; off >>= 1) acc += __shfl_xor(acc, off, 64);
    if (lane == 0) {
      const int row = n0 + wave * 4 + rr;
      float uval = (r[b * N + row] + 1e-12f) / acc;
      us[wave * 4 + rr] = uval;
      u_out[b * N + row] = uval;
    }
  }
  __syncthreads();   // us ready; vs fully consumed -> smem reusable as cpart

  float ul[4];
#pragma unroll
  for (int rr = 0; rr < 4; ++rr) ul[rr] = us[wave * 4 + rr];

  // Phase B: column partials from the SAME registers (no second K read).
  // Each wave covers all 2048 columns (4 it-groups x 64 lanes x 8 cols) over
  // its 4 rows; write per-wave partials to smem[wave][2048].
#pragma unroll
  for (int it = 0; it < 4; ++it) {
    float c0 = 0, c1 = 0, c2 = 0, c3 = 0, c4 = 0, c5 = 0, c6 = 0, c7 = 0;
#pragma unroll
    for (int rr = 0; rr < 4; ++rr) {
      uint4 w = kr[rr][it];
      float uv = ul[rr];
      c0 += bflo(w.x) * uv; c1 += bfhi(w.x) * uv;
      c2 += bflo(w.y) * uv; c3 += bfhi(w.y) * uv;
      c4 += bflo(w.z) * uv; c5 += bfhi(w.z) * uv;
      c6 += bflo(w.w) * uv; c7 += bfhi(w.w) * uv;
    }
    float* dst = &smem[wave * 2048 + it * 512 + lane * 8];
    float4 o0; o0.x = c0; o0.y = c1; o0.z = c2; o0.w = c3;
    float4 o1; o1.x = c4; o1.y = c5; o1.z = c6; o1.w = c7;
    ((float4*)dst)[0] = o0;
    ((float4*)dst)[1] = o1;
  }
  __syncthreads();

  // Cross-wave reduce (4 partials per column) + coalesced part write.
  const float4* cp4 = (const float4*)smem;   // [4][512] float4
  float4* Pout = (float4*)(part + (size_t)(b * CHUNKS + chunk) * M);
#pragma unroll
  for (int h = 0; h < 2; ++h) {
    const int idx = h * 256 + t;
    float4 a = cp4[idx], bb = cp4[512 + idx], cc = cp4[1024 + idx], dd = cp4[1536 + idx];
    float4 s;
    s.x = (a.x + bb.x) + (cc.x + dd.x);
    s.y = (a.y + bb.y) + (cc.y + dd.y);
    s.z = (a.z + bb.z) + (cc.z + dd.z);
    s.w = (a.w + bb.w) + (cc.w + dd.w);
    Pout[idx] = s;
  }
}

// ---------------- v-finalize: v[b,m] = (c[b,m]+1e-12) / sum_chunks partial ----------------
template <int NCH>
__global__ __launch_bounds__(256) void v_fin(const float* __restrict__ part,
                                             const float* __restrict__ c,
                                             float* __restrict__ v) {
  const int g = blockIdx.x * 256 + threadIdx.x;   // 0..B*M-1
  const int b = g >> 11, m = g & (M - 1);
  const float* p = part + (size_t)b * NCH * M + m;
  float s0 = 0.f, s1 = 0.f, s2 = 0.f, s3 = 0.f;
#pragma unroll 4
  for (int ch = 0; ch < NCH; ch += 4) {
    s0 += p[(size_t)(ch + 0) * M];
    s1 += p[(size_t)(ch + 1) * M];
    s2 += p[(size_t)(ch + 2) * M];
    s3 += p[(size_t)(ch + 3) * M];
  }
  v[g] = (c[g] + 1e-12f) / ((s0 + s1) + (s2 + s3));
}

// ---------------- final: T = u[n] * exp(-cost/eps) * v[m], exact from fp32 cost ----------------
__global__ __launch_bounds__(256) void final_T(const float* __restrict__ cost,
                                               const float* __restrict__ u,
                                               const float* __restrict__ v,
                                               float* __restrict__ out) {
  const int b = blockIdx.z, n = blockIdx.y;
  const int m4 = blockIdx.x * 256 + threadIdx.x;  // 0..M/4-1
  const float un = u[b * N + n];
  float4 vv = ((const float4*)(v + (size_t)b * M))[m4];
  const size_t off = ((size_t)(b * N + n) * M) / 4 + m4;
  float4 cc = ((const float4*)cost)[off];
  float4 o;
  o.x = un * vv.x * exp2f(cc.x * C2);
  o.y = un * vv.y * exp2f(cc.y * C2);
  o.z = un * vv.z * exp2f(cc.z * C2);
  o.w = un * vv.w * exp2f(cc.w * C2);
  ((float4*)out)[off] = o;
}

// ---------------- fallback (ws too small for K): stream fp32 cost ----------------
// Old geometry: 64 chunks x 32 rows, two passes over cost per iteration.
template <bool FIRST>
__global__ __launch_bounds__(256) void iter_fused_cost(const float* __restrict__ cost,
                                                       const float* __restrict__ r,
                                                       const float* __restrict__ v,
                                                       float* __restrict__ u_out,
                                                       float* __restrict__ part) {
  const int b = blockIdx.y, chunk = blockIdx.x;
  const int n0 = chunk * 32;
  const int t = threadIdx.x;
  __shared__ float vs[M];
  __shared__ float us[32];
  if (FIRST) {
    float4 one; one.x = one.y = one.z = one.w = 1.0f;
    ((float4*)vs)[t] = one; ((float4*)vs)[t + 256] = one;
  } else {
    const float4* vv = (const float4*)(v + (size_t)b * M);
    ((float4*)vs)[t] = vv[t]; ((float4*)vs)[t + 256] = vv[t + 256];
  }
  __syncthreads();
  const int wave = t >> 6, lane = t & 63;
  float vreg[32];
#pragma unroll
  for (int it = 0; it < 4; ++it) {
    float4 a = ((const float4*)vs)[it * 128 + lane * 2];
    float4 c = ((const float4*)vs)[it * 128 + lane * 2 + 1];
    vreg[it * 8 + 0] = a.x; vreg[it * 8 + 1] = a.y; vreg[it * 8 + 2] = a.z; vreg[it * 8 + 3] = a.w;
    vreg[it * 8 + 4] = c.x; vreg[it * 8 + 5] = c.y; vreg[it * 8 + 6] = c.z; vreg[it * 8 + 7] = c.w;
  }
#pragma unroll
  for (int rr = 0; rr < 8; ++rr) {
    const int lrow = wave * 8 + rr;
    const int row = n0 + lrow;
    const float4* Cr = (const float4*)(cost + (size_t)(b * N + row) * M);
    float acc = 0.f;
#pragma unroll
    for (int it = 0; it < 4; ++it) {
      float4 a = Cr[it * 128 + lane * 2];
      float4 c = Cr[it * 128 + lane * 2 + 1];
      acc += exp2f(a.x * C2) * vreg[it * 8 + 0] + exp2f(a.y * C2) * vreg[it * 8 + 1]
           + exp2f(a.z * C2) * vreg[it * 8 + 2] + exp2f(a.w * C2) * vreg[it * 8 + 3]
           + exp2f(c.x * C2) * vreg[it * 8 + 4] + exp2f(c.y * C2) * vreg[it * 8 + 5]
           + exp2f(c.z * C2) * vreg[it * 8 + 6] + exp2f(c.w * C2) * vreg[it * 8 + 7];
    }
#pragma unroll
    for (int off = 32; off; off >>= 1) acc += __shfl_xor(acc, off, 64);
    if (lane == 0) {
      float uval = (r[b * N + row] + 1e-12f) / acc;
      us[lrow] = uval;
      u_out[b * N + row] = uval;
    }
  }
  __syncthreads();
  float acc8[8] = {0, 0, 0, 0, 0, 0, 0, 0};
  const float4* Cb = (const float4*)(cost + (size_t)(b * N + n0) * M) + t * 2;
#pragma unroll 2
  for (int n = 0; n < 32; ++n) {
    float4 a = Cb[(size_t)n * (M / 4)];
    float4 c = Cb[(size_t)n * (M / 4) + 1];
    float uval = us[n];
    acc8[0] += exp2f(a.x * C2) * uval; acc8[1] += exp2f(a.y * C2) * uval;
    acc8[2] += exp2f(a.z * C2) * uval; acc8[3] += exp2f(a.w * C2) * uval;
    acc8[4] += exp2f(c.x * C2) * uval; acc8[5] += exp2f(c.y * C2) * uval;
    acc8[6] += exp2f(c.z * C2) * uval; acc8[7] += exp2f(c.w * C2) * uval;
  }
  float4* P = (float4*)(part + (size_t)(b * 64 + chunk) * M) + t * 2;
  float4 o0; o0.x = acc8[0]; o0.y = acc8[1]; o0.z = acc8[2]; o0.w = acc8[3];
  float4 o1; o1.x = acc8[4]; o1.y = acc8[5]; o1.z = acc8[6]; o1.w = acc8[7];
  P[0] = o0; P[1] = o1;
}

extern "C" void kernel_launch(void* const* d_in, const int* in_sizes, int n_in,
                              void* d_out, int out_size, void* d_ws, size_t ws_size,
                              hipStream_t stream) {
  const float* cost = (const float*)d_in[0];
  const float* r    = (const float*)d_in[1];
  const float* c    = (const float*)d_in[2];
  float* out        = (float*)d_out;
  char* ws          = (char*)d_ws;

  const size_t K_bytes    = (size_t)B * N * M * 2;           // 128 MiB bf16 K
  const size_t u_bytes    = (size_t)B * N * 4;
  const size_t v_bytes    = (size_t)B * M * 4;
  const size_t part_bytes = (size_t)B * CHUNKS * M * 4;      // 16 MiB
  const size_t need_main  = K_bytes + u_bytes + v_bytes + part_bytes;
  const bool useK = (ws_size >= need_main);                  // ws_size constant across calls

  uint4* K; float *u, *v, *part;
  if (useK) {
    K = (uint4*)ws;
    u = (float*)(ws + K_bytes);
  } else {
    K = nullptr;
    u = (float*)ws;
  }
  v = u + (size_t)B * N;
  part = v + (size_t)B * M;

  if (useK) {
    init_K<<<dim3((B * (size_t)N * M) / (256 * 16)), 256, 0, stream>>>(cost, K);
    iter_fused<true><<<dim3(CHUNKS, B), 256, 0, stream>>>(K, r, v, u, part);
    v_fin<CHUNKS><<<dim3(B * M / 256), 256, 0, stream>>>(part, c, v);
    for (int it = 1; it < MAX_ITER; ++it) {
      iter_fused<false><<<dim3(CHUNKS, B), 256, 0, stream>>>(K, r, v, u, part);
      v_fin<CHUNKS><<<dim3(B * M / 256), 256, 0, stream>>>(part, c, v);
    }
  } else {
    iter_fused_cost<true><<<dim3(64, B), 256, 0, stream>>>(cost, r, v, u, part);
    v_fin<64><<<dim3(B * M / 256), 256, 0, stream>>>(part, c, v);
    for (int it = 1; it < MAX_ITER; ++it) {
      iter_fused_cost<false><<<dim3(64, B), 256, 0, stream>>>(cost, r, v, u, part);
      v_fin<64><<<dim3(B * M / 256), 256, 0, stream>>>(part, c, v);
    }
  }

  final_T<<<dim3(M / 1024, N, B), 256, 0, stream>>>(cost, u, v, out);
}